// Round 8
// baseline (1862.572 us; speedup 1.0000x reference)
//
#include <hip/hip_runtime.h>
#include <hip/hip_bf16.h>
#include <hip/hip_cooperative_groups.h>

namespace cg = cooperative_groups;

#define N_NODES 100000
#define N_EDGES 1600000
#define F_IN    700
#define NKB0    22          // ceil(700/32)
#define HDIM    128
#define SCAN_B  256
#define NB_SCAN ((N_NODES + SCAN_B - 1) / SCAN_B)   // 391
#define NSHARD  64          // stats shards: stats[NSHARD][256] (sum | sumsq@+128)
#define CNB     1024        // cooperative grid: 4 blocks/CU
#define CITER   25          // node-iters per block
#define CNPB    (CITER * 4) // 100 nodes per block; 1024*100 >= N_NODES

typedef _Float16 half8 __attribute__((ext_vector_type(8)));
typedef _Float16 half4 __attribute__((ext_vector_type(4)));
typedef float floatx4 __attribute__((ext_vector_type(4)));

// async global->LDS, 16B per lane; dst slot = wave-uniform base + lane*16
__device__ __forceinline__ void cp16(const void* g, void* l) {
    __builtin_amdgcn_global_load_lds(
        (const __attribute__((address_space(1))) void*)g,
        (__attribute__((address_space(3))) void*)l, 16, 0, 0);
}

// ---------------------------------------------------------------- CSR build
__global__ void count_edges(const int* __restrict__ graph, int* __restrict__ cnt) {
    int e = blockIdx.x * blockDim.x + threadIdx.x;
    if (e < N_EDGES) atomicAdd(&cnt[graph[2 * e + 1]], 1);
}

__global__ void scan1(const int* __restrict__ cnt, int* __restrict__ incl,
                      int* __restrict__ blk) {
    __shared__ int s[SCAN_B];
    int tid = threadIdx.x;
    int i = blockIdx.x * SCAN_B + tid;
    s[tid] = (i < N_NODES) ? cnt[i] : 0;
    __syncthreads();
    for (int off = 1; off < SCAN_B; off <<= 1) {
        int t = (tid >= off) ? s[tid - off] : 0;
        __syncthreads();
        s[tid] += t;
        __syncthreads();
    }
    if (i < N_NODES) incl[i] = s[tid];
    if (tid == SCAN_B - 1) blk[blockIdx.x] = s[tid];
}

__global__ void scan2(const int* __restrict__ blk, int* __restrict__ blkoff) {
    __shared__ int s[512];
    int tid = threadIdx.x;
    s[tid] = (tid < NB_SCAN) ? blk[tid] : 0;
    __syncthreads();
    for (int off = 1; off < 512; off <<= 1) {
        int t = (tid >= off) ? s[tid - off] : 0;
        __syncthreads();
        s[tid] += t;
        __syncthreads();
    }
    if (tid < NB_SCAN) blkoff[tid] = (tid == 0) ? 0 : s[tid - 1];
}

__global__ void scan3(const int* __restrict__ incl, const int* __restrict__ blkoff,
                      int* __restrict__ row_ptr) {
    int i = blockIdx.x * SCAN_B + threadIdx.x;
    if (i < N_NODES) {
        row_ptr[i + 1] = incl[i] + blkoff[i >> 8];
        if (i == 0) row_ptr[0] = 0;
    }
}

__global__ void fill_edges(const int* __restrict__ graph, const int* __restrict__ row_ptr,
                           int* __restrict__ cursor, int* __restrict__ esrc) {
    int e = blockIdx.x * blockDim.x + threadIdx.x;
    if (e < N_EDGES) {
        int src = graph[2 * e];
        int dst = graph[2 * e + 1];
        esrc[row_ptr[dst] + atomicAdd(&cursor[dst], 1)] = src;
    }
}

// ------------------- weight packs: tile-major, XOR-swizzled LDS image (fp16)
__global__ void build_wtp0(const float* __restrict__ Wn, const float* __restrict__ Ws,
                           _Float16* __restrict__ out) {
    int q = blockIdx.x * blockDim.x + threadIdx.x;
    if (q >= NKB0 * 256 * 4) return;
    int kb = q >> 10;
    int r  = (q >> 2) & 255;
    int cc = q & 3;
    int k0 = kb * 32 + (cc ^ ((r >> 1) & 3)) * 8;
    half8 v;
    #pragma unroll
    for (int e = 0; e < 8; e++) {
        int k = k0 + e;
        float f = 0.0f;
        if (k < F_IN) f = (r < 128) ? Wn[k * 128 + r] : Ws[k * 128 + (r - 128)];
        v[e] = (_Float16)f;
    }
    *(half8*)&out[(size_t)q * 8] = v;
}

__global__ void build_wtpl(const float* __restrict__ Wn, const float* __restrict__ Ws,
                           _Float16* __restrict__ out) {
    int q = blockIdx.x * blockDim.x + threadIdx.x;
    if (q >= 3 * 4 * 256 * 4) return;
    int l = q >> 12;
    int rem = q & 4095;
    int kb = rem >> 10;
    int r  = (rem >> 2) & 255;
    int cc = rem & 3;
    int k0 = kb * 32 + (cc ^ ((r >> 1) & 3)) * 8;
    half8 v;
    #pragma unroll
    for (int e = 0; e < 8; e++) {
        int k = k0 + e;
        float f = (r < 128) ? Wn[l * 16384 + k * 128 + r]
                            : Ws[l * 16384 + k * 128 + (r - 128)];
        v[e] = (_Float16)f;
    }
    *(half8*)&out[(size_t)q * 8] = v;
}

// ---- layer-0 GEMM, UN-SPLIT N: M128 x N256, 512 threads (8 waves, 2x4).
__global__ __launch_bounds__(512) void gemm0_nu(
    const float* __restrict__ A, int M, int K,
    const _Float16* __restrict__ Wtp, const float* __restrict__ bias,
    const float* __restrict__ zbuf,
    _Float16* __restrict__ Cn, _Float16* __restrict__ Cs) {
    __shared__ char sbuf[2][32768];   // A fp32 [0,16384), B fp16 [16384,32768)

    int tid = threadIdx.x;
    int wave = tid >> 6, lane = tid & 63;
    int lm = lane & 15, quad = lane >> 4;
    int wm = wave >> 2, wn = wave & 3;      // 2x4 waves: 64 rows x 64 cols each
    long row0 = (long)blockIdx.x * 128;

    floatx4 acc[4][4] = {};

    auto stage = [&](int kb, char* buf) {
        #pragma unroll
        for (int pass = 0; pass < 2; pass++) {
            int q = pass * 512 + tid;
            int r = q >> 3, cc = q & 7;
            int ccg = cc ^ (r & 7);
            long grow = row0 + r;
            if (grow >= M) grow = 0;        // clamp: uniform load count per wave
            int gk = kb * 32 + ccg * 4;
            const float* src = (gk + 4 <= K) ? (A + grow * (long)K + gk) : zbuf;
            cp16(src, buf + pass * 8192 + wave * 1024);
        }
        const _Float16* wsrc = Wtp + (size_t)kb * 8192;
        #pragma unroll
        for (int pass = 0; pass < 2; pass++) {
            cp16(wsrc + (size_t)(pass * 512 + tid) * 8,
                 buf + 16384 + pass * 8192 + wave * 1024);
        }
    };

    stage(0, sbuf[0]);   // 4 loads in flight; waited inside the loop

    for (int kb = 0; kb < NKB0; kb++) {
        int p = kb & 1;
        if (kb + 1 < NKB0) {
            stage(kb + 1, sbuf[p ^ 1]);
            asm volatile("s_waitcnt vmcnt(4)\n\ts_barrier" ::: "memory");
        } else {
            asm volatile("s_waitcnt vmcnt(0)\n\ts_barrier" ::: "memory");
        }

        const float* Af = (const float*)sbuf[p];
        const _Float16* Bf = (const _Float16*)(sbuf[p] + 16384);
        half8 af[4];
        #pragma unroll
        for (int i = 0; i < 4; i++) {
            int row = wm * 64 + i * 16 + lm;
            int c0 = (quad * 2) ^ (row & 7);
            int c1 = (quad * 2 + 1) ^ (row & 7);
            floatx4 f0 = *(const floatx4*)&Af[row * 32 + c0 * 4];
            floatx4 f1 = *(const floatx4*)&Af[row * 32 + c1 * 4];
            af[i][0] = (_Float16)f0[0]; af[i][1] = (_Float16)f0[1];
            af[i][2] = (_Float16)f0[2]; af[i][3] = (_Float16)f0[3];
            af[i][4] = (_Float16)f1[0]; af[i][5] = (_Float16)f1[1];
            af[i][6] = (_Float16)f1[2]; af[i][7] = (_Float16)f1[3];
        }
        #pragma unroll
        for (int j = 0; j < 4; j++) {
            int brow = wn * 64 + j * 16 + lm;           // B-pack row 0..255
            int ch = quad ^ ((brow >> 1) & 3);
            half8 bf = *(const half8*)&Bf[brow * 32 + ch * 8];
            #pragma unroll
            for (int i = 0; i < 4; i++)
                acc[i][j] = __builtin_amdgcn_mfma_f32_16x16x32_f16(af[i], bf, acc[i][j], 0, 0, 0);
        }
        asm volatile("s_waitcnt lgkmcnt(0)\n\ts_barrier" ::: "memory");
    }

    #pragma unroll
    for (int i = 0; i < 4; i++) {
        long r0 = row0 + wm * 64 + i * 16 + quad * 4;
        #pragma unroll
        for (int j = 0; j < 4; j++) {
            int c = wn * 64 + j * 16 + lm;              // 0..255: Cn | Cs
            if (c >= 128) {
                float badd = bias[c - 128];
                #pragma unroll
                for (int rr = 0; rr < 4; rr++) {
                    long r = r0 + rr;
                    if (r < M) Cs[r * HDIM + (c - 128)] = (_Float16)(acc[i][j][rr] + badd);
                }
            } else {
                #pragma unroll
                for (int rr = 0; rr < 4; rr++) {
                    long r = r0 + rr;
                    if (r < M) Cn[r * HDIM + c] = (_Float16)acc[i][j][rr];
                }
            }
        }
    }
}

// ---- K=128 GEMM, UN-SPLIT N: M128 x N256, 512 threads; fp16 A staged once.
__global__ __launch_bounds__(512) void gemm16_nu(
    const _Float16* __restrict__ A, int M,
    const _Float16* __restrict__ Wtp, const float* __restrict__ bias,
    _Float16* __restrict__ Cn, _Float16* __restrict__ Cs) {
    __shared__ _Float16 sbuf[2][12288];  // A [0,4096), B [4096,12288) halves

    int tid = threadIdx.x;
    int wave = tid >> 6, lane = tid & 63;
    int lm = lane & 15, quad = lane >> 4;
    int wm = wave >> 2, wn = wave & 3;
    long row0 = (long)blockIdx.x * 128;

    floatx4 acc[4][4] = {};

    auto stage = [&](int kb, _Float16* buf) {
        {   // A: 512 chunks (r 0..127, slot cc 0..3), 1 cp16/thread
            int r = tid >> 2, cc = tid & 3;
            int ccg = cc ^ ((r >> 1) & 3);
            long grow = row0 + r;
            if (grow >= M) grow = 0;        // clamp: uniform load count per wave
            cp16(A + grow * (long)HDIM + kb * 32 + ccg * 8,
                 buf + wave * 512);
        }
        const _Float16* wsrc = Wtp + (size_t)kb * 8192;
        #pragma unroll
        for (int pass = 0; pass < 2; pass++) {
            cp16(wsrc + (size_t)(pass * 512 + tid) * 8,
                 buf + 4096 + pass * 4096 + wave * 512);
        }
    };

    stage(0, sbuf[0]);   // 3 loads in flight

    for (int kb = 0; kb < 4; kb++) {
        int p = kb & 1;
        if (kb + 1 < 4) {
            stage(kb + 1, sbuf[p ^ 1]);
            asm volatile("s_waitcnt vmcnt(3)\n\ts_barrier" ::: "memory");
        } else {
            asm volatile("s_waitcnt vmcnt(0)\n\ts_barrier" ::: "memory");
        }

        const _Float16* bp = sbuf[p];
        half8 af[4];
        #pragma unroll
        for (int i = 0; i < 4; i++) {
            int row = wm * 64 + i * 16 + lm;
            int ch = quad ^ ((row >> 1) & 3);
            af[i] = *(const half8*)&bp[row * 32 + ch * 8];
        }
        #pragma unroll
        for (int j = 0; j < 4; j++) {
            int brow = wn * 64 + j * 16 + lm;           // 0..255
            int ch = quad ^ ((brow >> 1) & 3);
            half8 bf = *(const half8*)&bp[4096 + brow * 32 + ch * 8];
            #pragma unroll
            for (int i = 0; i < 4; i++)
                acc[i][j] = __builtin_amdgcn_mfma_f32_16x16x32_f16(af[i], bf, acc[i][j], 0, 0, 0);
        }
        asm volatile("s_waitcnt lgkmcnt(0)\n\ts_barrier" ::: "memory");
    }

    #pragma unroll
    for (int i = 0; i < 4; i++) {
        long r0 = row0 + wm * 64 + i * 16 + quad * 4;
        #pragma unroll
        for (int j = 0; j < 4; j++) {
            int c = wn * 64 + j * 16 + lm;
            if (c >= 128) {
                float badd = bias[c - 128];
                #pragma unroll
                for (int rr = 0; rr < 4; rr++) {
                    long r = r0 + rr;
                    if (r < M) Cs[r * HDIM + (c - 128)] = (_Float16)(acc[i][j][rr] + badd);
                }
            } else {
                #pragma unroll
                for (int rr = 0; rr < 4; rr++) {
                    long r = r0 + rr;
                    if (r < M) Cn[r * HDIM + c] = (_Float16)acc[i][j][rr];
                }
            }
        }
    }
}

// ---- cooperative aggregate + BN stats + BN apply (no pre16 round-trip).
// 1024 blocks x 256 thr (4 blocks/CU, LDS 30.7KB). Phase1: gather + pre->LDS
// + stats (per-wave LDS accum, 1 sharded atomic/block). grid.sync().
// Phase2: fold shards -> scale/shift; apply relu(BN(pre)+res) -> out16.
__global__ __launch_bounds__(256, 4) void agg_bn_coop(
    const _Float16* __restrict__ hn, const int* __restrict__ row_ptr,
    const int* __restrict__ esrc, const _Float16* __restrict__ cs16,
    const _Float16* __restrict__ res16, _Float16* __restrict__ out16,
    float* __restrict__ stats, const float* __restrict__ gamma,
    const float* __restrict__ beta) {
    __shared__ _Float16 preL[CNPB][HDIM];        // 25.6 KB
    __shared__ float s1[4][HDIM], s2[4][HDIM];   // 4 KB
    __shared__ float ssc[HDIM], ssh[HDIM];       // 1 KB
    int tid = threadIdx.x;
    int wave = tid >> 6, lane = tid & 63;
    int eg = lane >> 4;            // edge slot 0..3
    int c8 = (lane & 15) * 8;      // channel group
    long nbase = (long)blockIdx.x * CNPB;

    for (int i = tid; i < 4 * HDIM; i += 256) {
        (&s1[0][0])[i] = 0.0f;
        (&s2[0][0])[i] = 0.0f;
    }
    __syncthreads();

    // ---------------- phase 1: aggregate into LDS + stats
    for (int it = 0; it < CITER; it++) {
        int nl = it * 4 + wave;
        long n = nbase + nl;
        if (n < N_NODES) {
            int start = row_ptr[n], end = row_ptr[n + 1];
            float acc[8] = {};
            for (int base = start; base < end; base += 16) {
                #pragma unroll
                for (int u = 0; u < 4; u++) {
                    int e = base + u * 4 + eg;
                    if (e < end) {
                        int s = esrc[e];
                        half8 v = *(const half8*)&hn[(size_t)s * HDIM + c8];
                        #pragma unroll
                        for (int i = 0; i < 8; i++) acc[i] += (float)v[i];
                    }
                }
            }
            #pragma unroll
            for (int i = 0; i < 8; i++) {
                acc[i] += __shfl_xor(acc[i], 16, 64);
                acc[i] += __shfl_xor(acc[i], 32, 64);
            }
            if (eg == 0) {
                float rd = 1.0f / (float)max(end - start, 1);
                half8 sv = *(const half8*)&cs16[(size_t)n * HDIM + c8];
                half8 h;
                #pragma unroll
                for (int i = 0; i < 8; i++) {
                    float pv = acc[i] * rd + (float)sv[i];
                    h[i] = (_Float16)pv;
                    s1[wave][c8 + i] += pv;
                    s2[wave][c8 + i] += pv * pv;
                }
                *(half8*)&preL[nl][c8] = h;
            }
        }
    }
    __syncthreads();
    if (tid < HDIM) {
        float a = s1[0][tid] + s1[1][tid] + s1[2][tid] + s1[3][tid];
        float b = s2[0][tid] + s2[1][tid] + s2[2][tid] + s2[3][tid];
        float* sh = stats + (size_t)(blockIdx.x & (NSHARD - 1)) * 256;
        atomicAdd(&sh[tid], a);
        atomicAdd(&sh[128 + tid], b);
    }

    cg::this_grid().sync();

    // ---------------- phase 2: finalize scale/shift, apply to own nodes
    if (tid < HDIM) {
        float s = 0.0f, s2v = 0.0f;
        #pragma unroll 8
        for (int k = 0; k < NSHARD; k++) {
            s   += stats[k * 256 + tid];
            s2v += stats[k * 256 + 128 + tid];
        }
        float mean = s / (float)N_NODES;
        float var = s2v / (float)N_NODES - mean * mean;
        float sc = rsqrtf(var + 1e-5f) * gamma[tid];
        ssc[tid] = sc;
        ssh[tid] = beta[tid] - mean * sc;
    }
    __syncthreads();

    for (int idx = tid; idx < CNPB * 16; idx += 256) {
        int nl = idx >> 4;
        int cc8 = (idx & 15) * 8;
        long n = nbase + nl;
        if (n < N_NODES) {
            half8 v = *(const half8*)&preL[nl][cc8];
            half8 h;
            if (res16) {
                half8 rv = *(const half8*)&res16[(size_t)n * HDIM + cc8];
                #pragma unroll
                for (int i = 0; i < 8; i++) {
                    float x = (float)v[i] * ssc[cc8 + i] + ssh[cc8 + i] + (float)rv[i];
                    h[i] = (_Float16)fmaxf(x, 0.0f);
                }
            } else {
                #pragma unroll
                for (int i = 0; i < 8; i++) {
                    float x = (float)v[i] * ssc[cc8 + i] + ssh[cc8 + i];
                    h[i] = (_Float16)fmaxf(x, 0.0f);
                }
            }
            *(half8*)&out16[(size_t)n * HDIM + cc8] = h;
        }
    }
}

// ------------------------- MLP head with fused Z-stats (sharded, C=64)
__global__ __launch_bounds__(256) void mlp_gemm(const _Float16* __restrict__ H,
                                                const float* __restrict__ W1,
                                                const float* __restrict__ b1,
                                                float* __restrict__ Z,
                                                float* __restrict__ stats, int M) {
    __shared__ float hs[64 * 132];
    __shared__ float ws[128 * 64];
    __shared__ float zs1[16][64], zs2[16][64];
    int tid = threadIdx.x;
    int tx = tid & 15;
    int ty = tid >> 4;
    int row0 = blockIdx.x * 64;

    #pragma unroll
    for (int t = 0; t < 8; t++) {
        int f = tid + t * 256;
        int r = f >> 4, c4 = (f & 15) * 4;
        *(float4*)&ws[r * 64 + c4] = *(const float4*)&W1[r * 64 + c4];
    }
    #pragma unroll
    for (int t = 0; t < 4; t++) {
        int f = tid + t * 256;
        int r = f >> 4, c8 = (f & 15) * 8;
        int gr = row0 + r;
        if (gr < M) {
            half8 hv = *(const half8*)&H[(size_t)gr * HDIM + c8];
            #pragma unroll
            for (int i = 0; i < 8; i++) hs[r * 132 + c8 + i] = (float)hv[i];
        } else {
            #pragma unroll
            for (int i = 0; i < 8; i++) hs[r * 132 + c8 + i] = 0.0f;
        }
    }
    __syncthreads();

    float acc[4][4] = {};
    for (int k = 0; k < 128; k++) {
        float a[4];
        #pragma unroll
        for (int i = 0; i < 4; i++) a[i] = hs[(ty * 4 + i) * 132 + k];
        float4 b4 = *(const float4*)&ws[k * 64 + tx * 4];
        #pragma unroll
        for (int i = 0; i < 4; i++) {
            acc[i][0] += a[i] * b4.x; acc[i][1] += a[i] * b4.y;
            acc[i][2] += a[i] * b4.z; acc[i][3] += a[i] * b4.w;
        }
    }
    float4 bb = *(const float4*)&b1[tx * 4];
    float cs[4] = {}, cq[4] = {};
    #pragma unroll
    for (int i = 0; i < 4; i++) {
        int r = row0 + ty * 4 + i;
        if (r < M) {
            float v0 = acc[i][0] + bb.x;
            float v1 = acc[i][1] + bb.y;
            float v2 = acc[i][2] + bb.z;
            float v3 = acc[i][3] + bb.w;
            float4 v = {v0, v1, v2, v3};
            *(float4*)&Z[(size_t)r * 64 + tx * 4] = v;
            cs[0] += v0; cq[0] += v0 * v0;
            cs[1] += v1; cq[1] += v1 * v1;
            cs[2] += v2; cq[2] += v2 * v2;
            cs[3] += v3; cq[3] += v3 * v3;
        }
    }
    #pragma unroll
    for (int j = 0; j < 4; j++) {
        zs1[ty][tx * 4 + j] = cs[j];
        zs2[ty][tx * 4 + j] = cq[j];
    }
    __syncthreads();
    if (tid < 64) {
        float a = 0.0f, b = 0.0f;
        #pragma unroll
        for (int k = 0; k < 16; k++) { a += zs1[k][tid]; b += zs2[k][tid]; }
        float* sh = stats + (size_t)(blockIdx.x & (NSHARD - 1)) * 256;
        atomicAdd(&sh[tid], a);
        atomicAdd(&sh[128 + tid], b);
    }
}

// out[n] = relu(bn(Z[n,:])) . W2 + b2  — BN finalize+apply fused into the dot
__global__ void final_out(const float* __restrict__ Z,
                          const float* __restrict__ stats,
                          const float* __restrict__ gamma, const float* __restrict__ beta,
                          const float* __restrict__ W2, const float* __restrict__ b2,
                          float* __restrict__ out, int M) {
    __shared__ float ssc[64], ssh[64], sw[64];
    int tid = threadIdx.x;
    if (tid < 64) {
        float s = 0.0f, s2 = 0.0f;
        #pragma unroll 8
        for (int k = 0; k < NSHARD; k++) {
            s  += stats[k * 256 + tid];
            s2 += stats[k * 256 + 128 + tid];
        }
        float mean = s / (float)M;
        float var = s2 / (float)M - mean * mean;
        float sc = rsqrtf(var + 1e-5f) * gamma[tid];
        ssc[tid] = sc;
        ssh[tid] = beta[tid] - mean * sc;
        sw[tid] = W2[tid];
    }
    __syncthreads();
    int n = blockIdx.x * 4 + (tid >> 6);
    int lane = tid & 63;
    if (n >= N_NODES) return;
    float z = Z[(size_t)n * 64 + lane] * ssc[lane] + ssh[lane];
    z = fmaxf(z, 0.0f);
    float v = z * sw[lane];
    #pragma unroll
    for (int off = 32; off >= 1; off >>= 1) v += __shfl_down(v, off, 64);
    if (lane == 0) out[n] = v + b2[0];
}

// ------------------------------------------------------------------ driver
extern "C" void kernel_launch(void* const* d_in, const int* in_sizes, int n_in,
                              void* d_out, int out_size, void* d_ws, size_t ws_size,
                              hipStream_t stream) {
    const float* X       = (const float*)d_in[0];
    const int*   graph   = (const int*)d_in[1];
    const float* Wself0  = (const float*)d_in[2];
    const float* Wneigh0 = (const float*)d_in[3];
    const float* b0      = (const float*)d_in[4];
    const float* Wself   = (const float*)d_in[5];
    const float* Wneigh  = (const float*)d_in[6];
    const float* bvec    = (const float*)d_in[7];
    const float* bn_g    = (const float*)d_in[8];
    const float* bn_b    = (const float*)d_in[9];
    const float* W1      = (const float*)d_in[10];
    const float* b1      = (const float*)d_in[11];
    const float* bng1    = (const float*)d_in[12];
    const float* bnb1    = (const float*)d_in[13];
    const float* W2      = (const float*)d_in[14];
    const float* b2      = (const float*)d_in[15];
    float* out = (float*)d_out;

    size_t off = 0;
    auto alloc = [&](size_t bytes) {
        void* p = (char*)d_ws + off;
        off += (bytes + 255) & ~(size_t)255;
        return p;
    };
    int* cnt     = (int*)alloc(N_NODES * 4);
    int* cursor  = (int*)alloc(N_NODES * 4);
    int* row_ptr = (int*)alloc((N_NODES + 1) * 4);
    int* incl    = (int*)alloc(N_NODES * 4);
    int* blk     = (int*)alloc(NB_SCAN * 4);
    int* blkoff  = (int*)alloc(NB_SCAN * 4);
    int* esrc    = (int*)alloc((size_t)N_EDGES * 4);
    _Float16* cs16  = (_Float16*)alloc((size_t)N_NODES * HDIM * 2); // 25.6 MB
    _Float16* h16A  = (_Float16*)alloc((size_t)N_NODES * HDIM * 2); // 25.6 MB
    _Float16* h16B  = (_Float16*)alloc((size_t)N_NODES * HDIM * 2);
    _Float16* hn16  = (_Float16*)alloc((size_t)N_NODES * HDIM * 2);
    float*    Z     = (float*)alloc((size_t)N_NODES * 64 * 4);
    _Float16* Wtp0  = (_Float16*)alloc((size_t)NKB0 * 8192 * 2);
    _Float16* Wtpl  = (_Float16*)alloc((size_t)3 * 4 * 8192 * 2);
    float*    zbuf  = (float*)alloc(256);
    float*    stats = (float*)alloc((size_t)NSHARD * 256 * 4);      // 64 KB

    const int EB = (N_EDGES + 255) / 256;
    const int GB2 = (N_NODES + 127) / 128;        // 782 (un-split N)
    const int AGB = (N_NODES + 3) / 4;            // 25000
    const size_t STB = (size_t)NSHARD * 256 * 4;

    // CSR build
    hipMemsetAsync(cnt, 0, N_NODES * 4, stream);
    hipMemsetAsync(cursor, 0, N_NODES * 4, stream);
    hipMemsetAsync(zbuf, 0, 256, stream);
    count_edges<<<EB, 256, 0, stream>>>(graph, cnt);
    scan1<<<NB_SCAN, SCAN_B, 0, stream>>>(cnt, incl, blk);
    scan2<<<1, 512, 0, stream>>>(blk, blkoff);
    scan3<<<NB_SCAN, SCAN_B, 0, stream>>>(incl, blkoff, row_ptr);
    fill_edges<<<EB, 256, 0, stream>>>(graph, row_ptr, cursor, esrc);

    // weight packs
    build_wtp0<<<(NKB0 * 1024 + 255) / 256, 256, 0, stream>>>(Wneigh0, Wself0, Wtp0);
    build_wtpl<<<(3 * 4096 + 255) / 256, 256, 0, stream>>>(Wneigh, Wself, Wtpl);

    _Float16* hc = h16A;
    _Float16* hx = h16B;

    // ---- layer 0 (K = 700, fp32 A direct, un-split N; coop agg+BN)
    gemm0_nu<<<GB2, 512, 0, stream>>>(X, N_NODES, F_IN, Wtp0, b0, zbuf, hn16, cs16);
    hipMemsetAsync(stats, 0, STB, stream);
    {
        const _Float16* res = nullptr;
        const float* g = bn_g; const float* b = bn_b;
        void* args[] = {(void*)&hn16, (void*)&row_ptr, (void*)&esrc, (void*)&cs16,
                        (void*)&res, (void*)&hc, (void*)&stats, (void*)&g, (void*)&b};
        hipLaunchCooperativeKernel((void*)agg_bn_coop, dim3(CNB), dim3(256),
                                   args, 0, stream);
    }

    // ---- layers 1..3 (K = 128, residual fp16, un-split N; coop agg+BN)
    for (int l = 0; l < 3; l++) {
        gemm16_nu<<<GB2, 512, 0, stream>>>(hc, N_NODES, Wtpl + (size_t)l * 32768,
                                           bvec + l * HDIM, hn16, cs16);
        hipMemsetAsync(stats, 0, STB, stream);
        const _Float16* res = hc;
        const float* g = bn_g + (l + 1) * HDIM;
        const float* b = bn_b + (l + 1) * HDIM;
        void* args[] = {(void*)&hn16, (void*)&row_ptr, (void*)&esrc, (void*)&cs16,
                        (void*)&res, (void*)&hx, (void*)&stats, (void*)&g, (void*)&b};
        hipLaunchCooperativeKernel((void*)agg_bn_coop, dim3(CNB), dim3(256),
                                   args, 0, stream);
        _Float16* t = hc; hc = hx; hx = t;
    }

    // ---- MLP head (Z-stats fused into mlp_gemm; BN finalize in final_out)
    hipMemsetAsync(stats, 0, STB, stream);
    mlp_gemm<<<(N_NODES + 63) / 64, 256, 0, stream>>>(hc, W1, b1, Z, stats, N_NODES);
    final_out<<<AGB, 256, 0, stream>>>(Z, stats, bng1, bnb1, W2, b2,
                                       out, N_NODES);
}